// Round 14
// baseline (1088.673 us; speedup 1.0000x reference)
//
#include <hip/hip_runtime.h>
#include <cstdint>

#define TOKS 4096
#define DIMD 2048
#define NE   16
#define HE   1408
#define HSH  2816
#define SLOTS 8192
#define SLOTP 8320
#define MAXT 2048

typedef unsigned short u16;
typedef __attribute__((ext_vector_type(8))) __bf16 bf16x8;
typedef __attribute__((ext_vector_type(4))) float  f32x4;

__device__ inline unsigned f2bf_pack(float a, float b) {
  unsigned ua = __builtin_bit_cast(unsigned, a);
  unsigned ub = __builtin_bit_cast(unsigned, b);
  ua = (ua + 0x7FFFu + ((ua >> 16) & 1u)) >> 16;
  ub = (ub + 0x7FFFu + ((ub >> 16) & 1u)) >> 16;
  return ua | (ub << 16);
}
__device__ inline u16 f2bf(float a) {
  unsigned ua = __builtin_bit_cast(unsigned, a);
  return (u16)((ua + 0x7FFFu + ((ua >> 16) & 1u)) >> 16);
}
__device__ inline float bf2f(u16 u) {
  return __builtin_bit_cast(float, (unsigned)u << 16);
}
__device__ inline void gload_lds16(const u16* g, u16* l) {
  __builtin_amdgcn_global_load_lds((const __attribute__((address_space(1))) void*)g,
                                   (__attribute__((address_space(3))) void*)l, 16, 0, 0);
}

// ---------------- gate (also emits xbf = bf16(x) as side output) ----------------
__global__ __launch_bounds__(64)
void gate2_kernel(const float* __restrict__ x, const float* __restrict__ gw,
                  float* __restrict__ probs, int* __restrict__ sel0, int* __restrict__ sel1,
                  float* __restrict__ wt0, float* __restrict__ wt1,
                  u16* __restrict__ xbf)
{
  const int t = blockIdx.x;
  const int l = threadIdx.x;
  const float4* xr = (const float4*)(x + (size_t)t * DIMD);
  float4 xv[8];
#pragma unroll
  for (int j = 0; j < 8; ++j) xv[j] = xr[j * 64 + l];

  uint2* xo = (uint2*)(xbf + (size_t)t * DIMD);
#pragma unroll
  for (int j = 0; j < 8; ++j) {
    uint2 q; q.x = f2bf_pack(xv[j].x, xv[j].y); q.y = f2bf_pack(xv[j].z, xv[j].w);
    xo[j * 64 + l] = q;
  }

  float sc[16];
#pragma unroll
  for (int e = 0; e < 16; ++e) {
    const float4* g = (const float4*)(gw + (size_t)e * DIMD);
    float s = 0.f;
#pragma unroll
    for (int j = 0; j < 8; ++j) {
      float4 gv = g[j * 64 + l];
      s += xv[j].x * gv.x + xv[j].y * gv.y + xv[j].z * gv.z + xv[j].w * gv.w;
    }
#pragma unroll
    for (int o = 32; o > 0; o >>= 1) s += __shfl_down(s, o);
    sc[e] = s;
  }
  if (l == 0) {
    float mx = sc[0];
#pragma unroll
    for (int e = 1; e < 16; ++e) mx = fmaxf(mx, sc[e]);
    float pe[16]; float sum = 0.f;
#pragma unroll
    for (int e = 0; e < 16; ++e) { pe[e] = __expf(sc[e] - mx); sum += pe[e]; }
    float inv = 1.f / sum;
    int b0 = -1, b1 = -1; float v0 = -1.f, v1 = -1.f;
#pragma unroll
    for (int e = 0; e < 16; ++e) {
      float p = pe[e] * inv;
      probs[t * 16 + e] = p;
      if (p > v0) { v1 = v0; b1 = b0; v0 = p; b0 = e; }
      else if (p > v1) { v1 = p; b1 = e; }
    }
    float wsum = v0 + v1 + 1e-9f;
    sel0[t] = b0; sel1[t] = b1;
    wt0[t] = v0 / wsum; wt1[t] = v1 / wsum;
  }
}

// ------------- per-expert count + load sum -------------
__global__ __launch_bounds__(256)
void expert_count(const int* __restrict__ sel0, const int* __restrict__ sel1,
                  const float* __restrict__ wt0, const float* __restrict__ wt1,
                  int* __restrict__ counts, float* __restrict__ loadsum)
{
  const int e = blockIdx.x, tid = threadIdx.x;
  int c = 0; float s = 0.f;
  for (int t = tid; t < TOKS; t += 256) {
    if (sel0[t] == e) { c++; s += wt0[t]; }
    else if (sel1[t] == e) { c++; s += wt1[t]; }
  }
  __shared__ int ci[256]; __shared__ float sf[256];
  ci[tid] = c; sf[tid] = s; __syncthreads();
  for (int d = 128; d > 0; d >>= 1) {
    if (tid < d) { ci[tid] += ci[tid + d]; sf[tid] += sf[tid + d]; }
    __syncthreads();
  }
  if (tid == 0) { counts[e] = ci[0]; loadsum[e] = sf[0]; }
}

// --- offsets + aux + XCD-packed tile tables (parallel scatter) ---
__global__ __launch_bounds__(256)
void offsets_aux(const float* __restrict__ probs, const int* __restrict__ counts,
                 const float* __restrict__ loadsum, int* __restrict__ offs,
                 int* __restrict__ te2, int* __restrict__ tn2, int* __restrict__ tm2,
                 int* __restrict__ te3, int* __restrict__ tn3, int* __restrict__ tm3,
                 float* __restrict__ out_aux)
{
  const int tid = threadIdx.x;
  for (int i = tid; i < MAXT; i += 256) { te2[i] = -1; te3[i] = -1; }

  float imp[16];
#pragma unroll
  for (int e = 0; e < 16; ++e) imp[e] = 0.f;
  for (int t = tid; t < TOKS; t += 256)
#pragma unroll
    for (int e = 0; e < 16; ++e) imp[e] += probs[t * 16 + e];

  __shared__ float red[256];
  __shared__ float impE[16];
  for (int e = 0; e < 16; ++e) {
    red[tid] = imp[e]; __syncthreads();
    for (int d = 128; d > 0; d >>= 1) {
      if (tid < d) red[tid] += red[tid + d];
      __syncthreads();
    }
    if (tid == 0) impE[e] = red[0];
    __syncthreads();
  }

  __shared__ int mtS[16];
  __shared__ int pEN2[352], pXS2[352], np2S;
  __shared__ int pEN3[256], pXS3[256], np3S;

  if (tid == 0) {
    int off = 0;
    for (int e = 0; e < 16; ++e) { offs[e] = off; off += counts[e]; }
    float tot = 0.f;
    for (int e = 0; e < 16; ++e) tot += loadsum[e];
    float aux = 0.f;
    for (int e = 0; e < 16; ++e) aux += (impE[e] / (float)TOKS) * (loadsum[e] / (tot + 1e-9f));
    *out_aux = 16.f * aux;

    int mt[16];
    for (int e = 0; e < 16; ++e) { mt[e] = (counts[e] + 127) >> 7; mtS[e] = mt[e]; }
    {
      int btot = 0;
      for (int e = 0; e < 16; ++e) btot += mt[e] * 22;
      int target = (btot + 7) >> 3;
      int x = 0, sp = 0, p = 0;
      for (int e = 0; e < 16; ++e) {
        if (!mt[e]) continue;
        for (int n = 0; n < 22; ++n) {
          pEN2[p] = e * 32 + n; pXS2[p] = x * 65536 + sp; ++p;
          sp += mt[e];
          if (sp >= target && x < 7) { ++x; sp = 0; }
        }
      }
      np2S = p;
    }
    {
      int btot = 0;
      for (int e = 0; e < 16; ++e) btot += mt[e] * 16;
      int target = (btot + 7) >> 3;
      int x = 0, sp = 0, p = 0;
      for (int e = 0; e < 16; ++e) {
        if (!mt[e]) continue;
        for (int n = 0; n < 16; ++n) {
          pEN3[p] = e * 32 + n; pXS3[p] = x * 65536 + sp; ++p;
          sp += mt[e];
          if (sp >= target && x < 7) { ++x; sp = 0; }
        }
      }
      np3S = p;
    }
  }
  __syncthreads();

  for (int p = tid; p < np2S; p += 256) {
    int e = pEN2[p] >> 5, n = pEN2[p] & 31;
    int x = pXS2[p] >> 16, sp = pXS2[p] & 65535;
    int mte = mtS[e];
    for (int m = 0; m < mte; ++m) {
      int tix = (sp + m) * 8 + x;
      te2[tix] = e; tn2[tix] = n; tm2[tix] = m << 7;
    }
  }
  for (int p = tid; p < np3S; p += 256) {
    int e = pEN3[p] >> 5, n = pEN3[p] & 31;
    int x = pXS3[p] >> 16, sp = pXS3[p] & 65535;
    int mte = mtS[e];
    for (int m = 0; m < mte; ++m) {
      int tix = (sp + m) * 8 + x;
      te3[tix] = e; tn3[tix] = n; tm3[tix] = m << 7;
    }
  }
}

// ------------- deterministic rank + scatter -------------
__global__ __launch_bounds__(256)
void rank_scatter(const int* __restrict__ sel0, const int* __restrict__ sel1,
                  const float* __restrict__ wt0, const float* __restrict__ wt1,
                  const int* __restrict__ offs, int* __restrict__ toklist2,
                  float* __restrict__ slotwt, int* __restrict__ tokslot)
{
  const int e = blockIdx.x, tid = threadIdx.x;
  const int t0 = tid * 16;
  unsigned flags = 0; int cloc = 0;
#pragma unroll
  for (int j = 0; j < 16; ++j) {
    int t = t0 + j;
    bool f = (sel0[t] == e) || (sel1[t] == e);
    flags |= ((unsigned)f) << j;
    cloc += f;
  }
  __shared__ int psum[256];
  psum[tid] = cloc; __syncthreads();
  for (int d = 1; d < 256; d <<= 1) {
    int v = (tid >= d) ? psum[tid - d] : 0;
    __syncthreads();
    psum[tid] += v;
    __syncthreads();
  }
  int r = offs[e] + psum[tid] - cloc;
  for (int j = 0; j < 16; ++j) {
    if ((flags >> j) & 1u) {
      int t = t0 + j;
      bool first = (sel0[t] == e);
      toklist2[r] = t;
      slotwt[r] = first ? wt0[t] : wt1[t];
      tokslot[2 * t + (first ? 0 : 1)] = r;
      r++;
    }
  }
}

// ------------- fp32 -> bf16 convert (contiguous) -------------
__global__ __launch_bounds__(256)
void cvt_f32_bf16(const float4* __restrict__ src, uint2* __restrict__ dst, int n4)
{
  int i = blockIdx.x * 256 + threadIdx.x;
  int stride = gridDim.x * 256;
  for (; i < n4; i += stride) {
    float4 v = src[i];
    uint2 p; p.x = f2bf_pack(v.x, v.y); p.y = f2bf_pack(v.z, v.w);
    dst[i] = p;
  }
}

// --- paired convert with 64-row chunk interleave ---
__global__ __launch_bounds__(256)
void cvt_pair(const float4* __restrict__ src1, const float4* __restrict__ src3,
              uint2* __restrict__ dst, int rows, int k4, int dstride4, int total4)
{
  int i = blockIdx.x * 256 + threadIdx.x;
  int stride = gridDim.x * 256;
  int per_e = rows * k4;
  for (; i < total4; i += stride) {
    int e = i / per_e;
    int rem = i - e * per_e;
    int j = rem / k4;
    int c = rem - j * k4;
    size_t dbase = (size_t)e * dstride4 + (size_t)(((j >> 6) * 128 + (j & 63))) * k4 + c;
    float4 v1 = src1[i];
    uint2 p1; p1.x = f2bf_pack(v1.x, v1.y); p1.y = f2bf_pack(v1.z, v1.w);
    dst[dbase] = p1;
    float4 v3 = src3[i];
    uint2 p3; p3.x = f2bf_pack(v3.x, v3.y); p3.y = f2bf_pack(v3.z, v3.w);
    dst[dbase + (size_t)64 * k4] = p3;
  }
}

// ------------- single-B bf16 MFMA GEMM (C = A * B^T), 128x128, BK=64 -------------
// MODE 0: dense A=xbf,B=sw13b(interleaved) -> fused silu -> U bf16
// MODE 1: dense A=U,B=sw2b -> out f32
// MODE 2: grouped A=xbf gathered via toklist2, B=w13b[e] -> fused silu*wt -> Act
// MODE 3: grouped A=Act (slot rows), B=w2b[e] -> Yslot bf16
template<int MODE>
__global__ __launch_bounds__(256, 4)
void gemm128(const u16* __restrict__ A, const u16* __restrict__ Bg,
             u16* __restrict__ Obf, float* __restrict__ Of,
             const int* __restrict__ counts, const int* __restrict__ offs,
             const int* __restrict__ te, const int* __restrict__ tn,
             const int* __restrict__ tm,
             const float* __restrict__ slotwt, const int* __restrict__ tok2)
{
  constexpr int KD = (MODE == 0) ? DIMD : (MODE == 1) ? HSH : (MODE == 2) ? DIMD : HE;
  constexpr int ND = (MODE == 0) ? 2 * HSH : (MODE == 1) ? DIMD : (MODE == 2) ? HSH : DIMD;
  constexpr bool FUSE = (MODE == 0 || MODE == 2);
  constexpr int NDOUT = (MODE == 0) ? HSH : (MODE == 2) ? HE : ND;

  __shared__ __align__(16) char sMemRaw[FUSE ? 33792 : 32768];
  u16* sA = (u16*)sMemRaw;
  u16* sB = sA + 128 * 64;

  const int tid  = threadIdx.x;
  const int lane = tid & 63;
  const int wave = tid >> 6;
  const int wm = wave >> 1, wn = wave & 1;

  int mbase, nbase;
  int e = 0, cnt = 0, arow0;
  const u16* B = Bg;
  if constexpr (MODE >= 2) {
    int tix = blockIdx.x;
    e = te[tix];
    if (e < 0) return;
    cnt = counts[e];
    mbase = tm[tix];
    nbase = tn[tix] * 128;
    arow0 = offs[e] + mbase;
    B = Bg + (size_t)e * ND * KD;
  } else {
    const int nx = gridDim.x;
    int bid = blockIdx.y * nx + blockIdx.x;
    int cpx = (nx * gridDim.y) >> 3;
    int swz = (bid & 7) * cpx + (bid >> 3);
    mbase = (swz / nx) * 128;
    nbase = (swz % nx) * 128;
    arow0 = mbase;
  }

  f32x4 acc[4][4];
#pragma unroll
  for (int i = 0; i < 4; ++i)
#pragma unroll
    for (int j = 0; j < 4; ++j) acc[i][j] = (f32x4){0.f, 0.f, 0.f, 0.f};

  const int srow  = lane >> 3;
  const int sslot = (lane & 7) ^ srow;
  const int scol  = sslot * 8;

  // per-thread staging row pointers (hoisted out of K loop)
  const u16* ArowP[4];
  const u16* BrowP[4];
  const u16* Bbase = B + (size_t)nbase * KD;
#pragma unroll
  for (int i = 0; i < 4; ++i) {
    int c = wave * 4 + i;
    int row = c * 8 + srow;
    if constexpr (MODE == 2) {
      int rg = arow0 + row;
      if (rg > SLOTS - 1) rg = SLOTS - 1;
      ArowP[i] = A + (size_t)tok2[rg] * KD + scol;   // gather from xbf
    } else if constexpr (MODE == 3) {
      int rg = arow0 + row;
      if (rg > SLOTS - 1) rg = SLOTS - 1;
      ArowP[i] = A + (size_t)rg * KD + scol;
    } else {
      ArowP[i] = A + (size_t)(arow0 + row) * KD + scol;
    }
    BrowP[i] = Bbase + (size_t)row * KD + scol;
  }

  for (int kb = 0; kb < KD; kb += 64) {
#pragma unroll
    for (int i = 0; i < 4; ++i) {
      int c = wave * 4 + i;
      gload_lds16(ArowP[i] + kb, &sA[c * 512]);
      gload_lds16(BrowP[i] + kb, &sB[c * 512]);
    }
    __syncthreads();

#pragma unroll
    for (int ks = 0; ks < 2; ++ks) {
      bf16x8 a[4], b[4];
#pragma unroll
      for (int mi = 0; mi < 4; ++mi) {
        int r = wm * 64 + mi * 16 + (lane & 15);
        int s = (ks * 4 + (lane >> 4)) ^ (r & 7);
        a[mi] = *(const bf16x8*)((const char*)sA + r * 128 + s * 16);
      }
#pragma unroll
      for (int ni = 0; ni < 4; ++ni) {
        int r = wn * 64 + ni * 16 + (lane & 15);
        int s = (ks * 4 + (lane >> 4)) ^ (r & 7);
        b[ni] = *(const bf16x8*)((const char*)sB + r * 128 + s * 16);
      }
#pragma unroll
      for (int mi = 0; mi < 4; ++mi)
#pragma unroll
        for (int ni = 0; ni < 4; ++ni)
          acc[mi][ni] = __builtin_amdgcn_mfma_f32_16x16x32_bf16(a[mi], b[ni], acc[mi][ni], 0, 0, 0);
    }
    __syncthreads();
  }

  const int lr4 = (lane >> 4) * 4;
  const int lc  = lane & 15;

  if constexpr (FUSE) {
    float* sX = (float*)sMemRaw;   // [128][66] f32
    if (wn == 1) {
#pragma unroll
      for (int mi = 0; mi < 4; ++mi)
#pragma unroll
        for (int ni = 0; ni < 4; ++ni)
#pragma unroll
          for (int r = 0; r < 4; ++r)
            sX[(wm * 64 + mi * 16 + lr4 + r) * 66 + ni * 16 + lc] = acc[mi][ni][r];
    }
    __syncthreads();
    if (wn == 0) {
#pragma unroll
      for (int mi = 0; mi < 4; ++mi) {
#pragma unroll
        for (int ni = 0; ni < 4; ++ni) {
#pragma unroll
          for (int r = 0; r < 4; ++r) {
            int lrow = wm * 64 + mi * 16 + lr4 + r;
            float h1 = acc[mi][ni][r];
            float h3 = sX[lrow * 66 + ni * 16 + lc];
            float u = (h1 / (1.f + __expf(-h1))) * h3;
            int col = (nbase >> 1) + ni * 16 + lc;
            if constexpr (MODE == 0) {
              Obf[(size_t)(mbase + lrow) * NDOUT + col] = f2bf(u);
            } else {
              int grow = mbase + lrow;
              if (grow < cnt) {
                u *= slotwt[arow0 + lrow];
                Obf[(size_t)(arow0 + lrow) * NDOUT + col] = f2bf(u);
              }
            }
          }
        }
      }
    }
  } else {
#pragma unroll
    for (int mi = 0; mi < 4; ++mi) {
#pragma unroll
      for (int ni = 0; ni < 4; ++ni) {
#pragma unroll
        for (int r = 0; r < 4; ++r) {
          int lrow = wm * 64 + mi * 16 + lr4 + r;
          int col  = nbase + wn * 64 + ni * 16 + lc;
          float v = acc[mi][ni][r];
          if constexpr (MODE == 1) {
            Of[(size_t)(mbase + lrow) * ND + col] = v;
          } else {
            int grow = mbase + lrow;
            if (grow < cnt) Obf[(size_t)(arow0 + lrow) * ND + col] = f2bf(v);
          }
        }
      }
    }
  }
}

// ------------- finalize: out[t] += Yslot[s0(t)] + Yslot[s1(t)] -------------
__global__ __launch_bounds__(256)
void finalize(const u16* __restrict__ Yslot, const int* __restrict__ tokslot,
              float* __restrict__ out)
{
  int i = blockIdx.x * 256 + threadIdx.x;
  int t = i >> 8;
  int c = (i & 255) * 8;
  int s0 = tokslot[2 * t], s1 = tokslot[2 * t + 1];
  uint4 a = *(const uint4*)(Yslot + (size_t)s0 * DIMD + c);
  uint4 b = *(const uint4*)(Yslot + (size_t)s1 * DIMD + c);
  const u16* ap = (const u16*)&a;
  const u16* bp = (const u16*)&b;
  float* op = out + (size_t)t * DIMD + c;
  float4 v0 = *(float4*)op, v1 = *(float4*)(op + 4);
  float vv[8] = {v0.x, v0.y, v0.z, v0.w, v1.x, v1.y, v1.z, v1.w};
#pragma unroll
  for (int j = 0; j < 8; ++j) vv[j] += bf2f(ap[j]) + bf2f(bp[j]);
  *(float4*)op = (float4){vv[0], vv[1], vv[2], vv[3]};
  *(float4*)(op + 4) = (float4){vv[4], vv[5], vv[6], vv[7]};
}

extern "C" void kernel_launch(void* const* d_in, const int* in_sizes, int n_in,
                              void* d_out, int out_size, void* d_ws, size_t ws_size,
                              hipStream_t stream) {
  const float* x      = (const float*)d_in[0];
  const float* gate_w = (const float*)d_in[1];
  const float* w1     = (const float*)d_in[2];
  const float* w2     = (const float*)d_in[3];
  const float* w3     = (const float*)d_in[4];
  const float* sw1    = (const float*)d_in[5];
  const float* sw2    = (const float*)d_in[6];
  const float* sw3    = (const float*)d_in[7];
  float* out = (float*)d_out;

  char* ws = (char*)d_ws;
  size_t o = 0;
  int*   counts   = (int*)(ws + o);   o += 256;
  int*   offsv    = (int*)(ws + o);   o += 256;
  float* loadsum  = (float*)(ws + o); o += 256;
  int*   te2      = (int*)(ws + o);   o += MAXT * 4;
  int*   tn2      = (int*)(ws + o);   o += MAXT * 4;
  int*   tm2      = (int*)(ws + o);   o += MAXT * 4;
  int*   te3      = (int*)(ws + o);   o += MAXT * 4;
  int*   tn3      = (int*)(ws + o);   o += MAXT * 4;
  int*   tm3      = (int*)(ws + o);   o += MAXT * 4;
  int*   sel0     = (int*)(ws + o);   o += TOKS * 4;
  int*   sel1     = (int*)(ws + o);   o += TOKS * 4;
  float* wt0      = (float*)(ws + o); o += TOKS * 4;
  float* wt1      = (float*)(ws + o); o += TOKS * 4;
  int*   tokslot  = (int*)(ws + o);   o += TOKS * 2 * 4;
  int*   toklist2 = (int*)(ws + o);   o += SLOTS * 4;
  float* slotwt   = (float*)(ws + o); o += SLOTS * 4;
  float* probs    = (float*)(ws + o); o += TOKS * 16 * 4;

  o = 1 << 20;
  u16* xbf   = (u16*)(ws + o); o += (size_t)TOKS * DIMD * 2;
  u16* Yslot = (u16*)(ws + o); o += (size_t)SLOTP * DIMD * 2;
  u16* w13b  = (u16*)(ws + o); o += (size_t)NE * HSH * DIMD * 2;
  u16* w2b   = (u16*)(ws + o); o += (size_t)NE * DIMD * HE * 2;
  u16* sw13b = (u16*)(ws + o); o += (size_t)(2 * HSH) * DIMD * 2;
  u16* sw2b  = (u16*)(ws + o); o += (size_t)DIMD * HSH * 2;
  u16* UA    = (u16*)(ws + o); o += (size_t)SLOTP * HSH * 2;

  // routing (fully deterministic, no atomics); gate also emits xbf
  gate2_kernel<<<TOKS, 64, 0, stream>>>(x, gate_w, probs, sel0, sel1, wt0, wt1, xbf);
  expert_count<<<NE, 256, 0, stream>>>(sel0, sel1, wt0, wt1, counts, loadsum);
  offsets_aux<<<1, 256, 0, stream>>>(probs, counts, loadsum, offsv,
                                     te2, tn2, tm2, te3, tn3, tm3,
                                     out + (size_t)TOKS * DIMD);
  rank_scatter<<<NE, 256, 0, stream>>>(sel0, sel1, wt0, wt1, offsv, toklist2, slotwt, tokslot);

  // shared expert (convert each B right before its consumer -> L3-hot)
  cvt_pair<<<2048, 256, 0, stream>>>((const float4*)sw1, (const float4*)sw3, (uint2*)sw13b,
                                     HSH, DIMD / 4, 0, HSH * DIMD / 4);
  gemm128<0><<<dim3(2 * HSH / 128, TOKS / 128), 256, 0, stream>>>(
      xbf, sw13b, UA, nullptr, nullptr, nullptr, nullptr, nullptr, nullptr, nullptr, nullptr);
  cvt_f32_bf16<<<1024, 256, 0, stream>>>((const float4*)sw2, (uint2*)sw2b, DIMD * HSH / 4);
  gemm128<1><<<dim3(DIMD / 128, TOKS / 128), 256, 0, stream>>>(
      UA, sw2b, nullptr, out, nullptr, nullptr, nullptr, nullptr, nullptr, nullptr, nullptr);

  // routed experts
  cvt_pair<<<4096, 256, 0, stream>>>((const float4*)w1, (const float4*)w3, (uint2*)w13b,
                                     HE, DIMD / 4, HSH * DIMD / 4, NE * HE * DIMD / 4);
  gemm128<2><<<dim3(MAXT), 256, 0, stream>>>(
      xbf, w13b, UA, nullptr, counts, offsv, te2, tn2, tm2, slotwt, toklist2);
  cvt_f32_bf16<<<4096, 256, 0, stream>>>((const float4*)w2, (uint2*)w2b, NE * DIMD * HE / 4);
  gemm128<3><<<dim3(MAXT), 256, 0, stream>>>(
      UA, w2b, Yslot, nullptr, counts, offsv, te3, tn3, tm3, nullptr, nullptr);
  finalize<<<TOKS * DIMD / 8 / 256, 256, 0, stream>>>(Yslot, tokslot, out);
}

// Round 15
// 759.435 us; speedup vs baseline: 1.4335x; 1.4335x over previous
//
#include <hip/hip_runtime.h>
#include <cstdint>

#define TOKS 4096
#define DIMD 2048
#define NE   16
#define HE   1408
#define HSH  2816
#define SLOTS 8192
#define SLOTP 8320
#define MAXT 2048

typedef unsigned short u16;
typedef __attribute__((ext_vector_type(8))) __bf16 bf16x8;
typedef __attribute__((ext_vector_type(4))) float  f32x4;

__device__ inline unsigned f2bf_pack(float a, float b) {
  unsigned ua = __builtin_bit_cast(unsigned, a);
  unsigned ub = __builtin_bit_cast(unsigned, b);
  ua = (ua + 0x7FFFu + ((ua >> 16) & 1u)) >> 16;
  ub = (ub + 0x7FFFu + ((ub >> 16) & 1u)) >> 16;
  return ua | (ub << 16);
}
__device__ inline u16 f2bf(float a) {
  unsigned ua = __builtin_bit_cast(unsigned, a);
  return (u16)((ua + 0x7FFFu + ((ua >> 16) & 1u)) >> 16);
}
__device__ inline float bf2f(u16 u) {
  return __builtin_bit_cast(float, (unsigned)u << 16);
}
__device__ inline void gload_lds16(const u16* g, u16* l) {
  __builtin_amdgcn_global_load_lds((const __attribute__((address_space(1))) void*)g,
                                   (__attribute__((address_space(3))) void*)l, 16, 0, 0);
}

// ---------------- gate (also emits xbf = bf16(x) as side output) ----------------
__global__ __launch_bounds__(64)
void gate2_kernel(const float* __restrict__ x, const float* __restrict__ gw,
                  float* __restrict__ probs, int* __restrict__ sel0, int* __restrict__ sel1,
                  float* __restrict__ wt0, float* __restrict__ wt1,
                  u16* __restrict__ xbf)
{
  const int t = blockIdx.x;
  const int l = threadIdx.x;
  const float4* xr = (const float4*)(x + (size_t)t * DIMD);
  float4 xv[8];
#pragma unroll
  for (int j = 0; j < 8; ++j) xv[j] = xr[j * 64 + l];

  uint2* xo = (uint2*)(xbf + (size_t)t * DIMD);
#pragma unroll
  for (int j = 0; j < 8; ++j) {
    uint2 q; q.x = f2bf_pack(xv[j].x, xv[j].y); q.y = f2bf_pack(xv[j].z, xv[j].w);
    xo[j * 64 + l] = q;
  }

  float sc[16];
#pragma unroll
  for (int e = 0; e < 16; ++e) {
    const float4* g = (const float4*)(gw + (size_t)e * DIMD);
    float s = 0.f;
#pragma unroll
    for (int j = 0; j < 8; ++j) {
      float4 gv = g[j * 64 + l];
      s += xv[j].x * gv.x + xv[j].y * gv.y + xv[j].z * gv.z + xv[j].w * gv.w;
    }
#pragma unroll
    for (int o = 32; o > 0; o >>= 1) s += __shfl_down(s, o);
    sc[e] = s;
  }
  if (l == 0) {
    float mx = sc[0];
#pragma unroll
    for (int e = 1; e < 16; ++e) mx = fmaxf(mx, sc[e]);
    float pe[16]; float sum = 0.f;
#pragma unroll
    for (int e = 0; e < 16; ++e) { pe[e] = __expf(sc[e] - mx); sum += pe[e]; }
    float inv = 1.f / sum;
    int b0 = -1, b1 = -1; float v0 = -1.f, v1 = -1.f;
#pragma unroll
    for (int e = 0; e < 16; ++e) {
      float p = pe[e] * inv;
      probs[t * 16 + e] = p;
      if (p > v0) { v1 = v0; b1 = b0; v0 = p; b0 = e; }
      else if (p > v1) { v1 = p; b1 = e; }
    }
    float wsum = v0 + v1 + 1e-9f;
    sel0[t] = b0; sel1[t] = b1;
    wt0[t] = v0 / wsum; wt1[t] = v1 / wsum;
  }
}

// ------------- per-expert count + load sum -------------
__global__ __launch_bounds__(256)
void expert_count(const int* __restrict__ sel0, const int* __restrict__ sel1,
                  const float* __restrict__ wt0, const float* __restrict__ wt1,
                  int* __restrict__ counts, float* __restrict__ loadsum)
{
  const int e = blockIdx.x, tid = threadIdx.x;
  int c = 0; float s = 0.f;
  for (int t = tid; t < TOKS; t += 256) {
    if (sel0[t] == e) { c++; s += wt0[t]; }
    else if (sel1[t] == e) { c++; s += wt1[t]; }
  }
  __shared__ int ci[256]; __shared__ float sf[256];
  ci[tid] = c; sf[tid] = s; __syncthreads();
  for (int d = 128; d > 0; d >>= 1) {
    if (tid < d) { ci[tid] += ci[tid + d]; sf[tid] += sf[tid + d]; }
    __syncthreads();
  }
  if (tid == 0) { counts[e] = ci[0]; loadsum[e] = sf[0]; }
}

// --- offsets + aux + XCD-packed tile tables (parallel scatter) ---
__global__ __launch_bounds__(256)
void offsets_aux(const float* __restrict__ probs, const int* __restrict__ counts,
                 const float* __restrict__ loadsum, int* __restrict__ offs,
                 int* __restrict__ te2, int* __restrict__ tn2, int* __restrict__ tm2,
                 int* __restrict__ te3, int* __restrict__ tn3, int* __restrict__ tm3,
                 float* __restrict__ out_aux)
{
  const int tid = threadIdx.x;
  for (int i = tid; i < MAXT; i += 256) { te2[i] = -1; te3[i] = -1; }

  float imp[16];
#pragma unroll
  for (int e = 0; e < 16; ++e) imp[e] = 0.f;
  for (int t = tid; t < TOKS; t += 256)
#pragma unroll
    for (int e = 0; e < 16; ++e) imp[e] += probs[t * 16 + e];

  __shared__ float red[256];
  __shared__ float impE[16];
  for (int e = 0; e < 16; ++e) {
    red[tid] = imp[e]; __syncthreads();
    for (int d = 128; d > 0; d >>= 1) {
      if (tid < d) red[tid] += red[tid + d];
      __syncthreads();
    }
    if (tid == 0) impE[e] = red[0];
    __syncthreads();
  }

  __shared__ int mtS[16];
  __shared__ int pEN2[352], pXS2[352], np2S;
  __shared__ int pEN3[256], pXS3[256], np3S;

  if (tid == 0) {
    int off = 0;
    for (int e = 0; e < 16; ++e) { offs[e] = off; off += counts[e]; }
    float tot = 0.f;
    for (int e = 0; e < 16; ++e) tot += loadsum[e];
    float aux = 0.f;
    for (int e = 0; e < 16; ++e) aux += (impE[e] / (float)TOKS) * (loadsum[e] / (tot + 1e-9f));
    *out_aux = 16.f * aux;

    int mt[16];
    for (int e = 0; e < 16; ++e) { mt[e] = (counts[e] + 127) >> 7; mtS[e] = mt[e]; }
    {
      int btot = 0;
      for (int e = 0; e < 16; ++e) btot += mt[e] * 22;
      int target = (btot + 7) >> 3;
      int x = 0, sp = 0, p = 0;
      for (int e = 0; e < 16; ++e) {
        if (!mt[e]) continue;
        for (int n = 0; n < 22; ++n) {
          pEN2[p] = e * 32 + n; pXS2[p] = x * 65536 + sp; ++p;
          sp += mt[e];
          if (sp >= target && x < 7) { ++x; sp = 0; }
        }
      }
      np2S = p;
    }
    {
      int btot = 0;
      for (int e = 0; e < 16; ++e) btot += mt[e] * 16;
      int target = (btot + 7) >> 3;
      int x = 0, sp = 0, p = 0;
      for (int e = 0; e < 16; ++e) {
        if (!mt[e]) continue;
        for (int n = 0; n < 16; ++n) {
          pEN3[p] = e * 32 + n; pXS3[p] = x * 65536 + sp; ++p;
          sp += mt[e];
          if (sp >= target && x < 7) { ++x; sp = 0; }
        }
      }
      np3S = p;
    }
  }
  __syncthreads();

  for (int p = tid; p < np2S; p += 256) {
    int e = pEN2[p] >> 5, n = pEN2[p] & 31;
    int x = pXS2[p] >> 16, sp = pXS2[p] & 65535;
    int mte = mtS[e];
    for (int m = 0; m < mte; ++m) {
      int tix = (sp + m) * 8 + x;
      te2[tix] = e; tn2[tix] = n; tm2[tix] = m << 7;
    }
  }
  for (int p = tid; p < np3S; p += 256) {
    int e = pEN3[p] >> 5, n = pEN3[p] & 31;
    int x = pXS3[p] >> 16, sp = pXS3[p] & 65535;
    int mte = mtS[e];
    for (int m = 0; m < mte; ++m) {
      int tix = (sp + m) * 8 + x;
      te3[tix] = e; tn3[tix] = n; tm3[tix] = m << 7;
    }
  }
}

// ------------- deterministic rank + scatter -------------
__global__ __launch_bounds__(256)
void rank_scatter(const int* __restrict__ sel0, const int* __restrict__ sel1,
                  const float* __restrict__ wt0, const float* __restrict__ wt1,
                  const int* __restrict__ offs, int* __restrict__ toklist2,
                  float* __restrict__ slotwt, int* __restrict__ tokslot)
{
  const int e = blockIdx.x, tid = threadIdx.x;
  const int t0 = tid * 16;
  unsigned flags = 0; int cloc = 0;
#pragma unroll
  for (int j = 0; j < 16; ++j) {
    int t = t0 + j;
    bool f = (sel0[t] == e) || (sel1[t] == e);
    flags |= ((unsigned)f) << j;
    cloc += f;
  }
  __shared__ int psum[256];
  psum[tid] = cloc; __syncthreads();
  for (int d = 1; d < 256; d <<= 1) {
    int v = (tid >= d) ? psum[tid - d] : 0;
    __syncthreads();
    psum[tid] += v;
    __syncthreads();
  }
  int r = offs[e] + psum[tid] - cloc;
  for (int j = 0; j < 16; ++j) {
    if ((flags >> j) & 1u) {
      int t = t0 + j;
      bool first = (sel0[t] == e);
      toklist2[r] = t;
      slotwt[r] = first ? wt0[t] : wt1[t];
      tokslot[2 * t + (first ? 0 : 1)] = r;
      r++;
    }
  }
}

// ------------- fp32 -> bf16 convert (contiguous) -------------
__global__ __launch_bounds__(256)
void cvt_f32_bf16(const float4* __restrict__ src, uint2* __restrict__ dst, int n4)
{
  int i = blockIdx.x * 256 + threadIdx.x;
  int stride = gridDim.x * 256;
  for (; i < n4; i += stride) {
    float4 v = src[i];
    uint2 p; p.x = f2bf_pack(v.x, v.y); p.y = f2bf_pack(v.z, v.w);
    dst[i] = p;
  }
}

// --- paired convert with 64-row chunk interleave ---
__global__ __launch_bounds__(256)
void cvt_pair(const float4* __restrict__ src1, const float4* __restrict__ src3,
              uint2* __restrict__ dst, int rows, int k4, int dstride4, int total4)
{
  int i = blockIdx.x * 256 + threadIdx.x;
  int stride = gridDim.x * 256;
  int per_e = rows * k4;
  for (; i < total4; i += stride) {
    int e = i / per_e;
    int rem = i - e * per_e;
    int j = rem / k4;
    int c = rem - j * k4;
    size_t dbase = (size_t)e * dstride4 + (size_t)(((j >> 6) * 128 + (j & 63))) * k4 + c;
    float4 v1 = src1[i];
    uint2 p1; p1.x = f2bf_pack(v1.x, v1.y); p1.y = f2bf_pack(v1.z, v1.w);
    dst[dbase] = p1;
    float4 v3 = src3[i];
    uint2 p3; p3.x = f2bf_pack(v3.x, v3.y); p3.y = f2bf_pack(v3.z, v3.w);
    dst[dbase + (size_t)64 * k4] = p3;
  }
}

// ------------- gather: copy bf16 token rows into slot-major layout -------------
__global__ __launch_bounds__(256)
void gather2(const u16* __restrict__ xbf, const int* __restrict__ toklist2,
             u16* __restrict__ Xg)
{
  int slot = blockIdx.x * 4 + (threadIdx.x >> 6);
  int l = threadIdx.x & 63;
  int tok = toklist2[slot];
  const uint2* srcr = (const uint2*)(xbf + (size_t)tok * DIMD);
  uint2* dstr = (uint2*)(Xg + (size_t)slot * DIMD);
#pragma unroll
  for (int j = 0; j < 8; ++j) dstr[j * 64 + l] = srcr[j * 64 + l];
}

// ------------- single-B bf16 MFMA GEMM (C = A * B^T), 128x128, BK=64 -------------
// MODE 0: dense A=xbf,B=sw13b(interleaved) -> fused silu -> U bf16
// MODE 1: dense A=U,B=sw2b -> out f32
// MODE 2: grouped A=Xg,B=w13b[e] -> fused silu*wt -> Act (XCD-packed table)
// MODE 3: grouped A=Act,B=w2b[e] -> Yslot bf16 (XCD-packed table)
template<int MODE>
__global__ __launch_bounds__(256, 4)
void gemm128(const u16* __restrict__ A, const u16* __restrict__ Bg,
             u16* __restrict__ Obf, float* __restrict__ Of,
             const int* __restrict__ counts, const int* __restrict__ offs,
             const int* __restrict__ te, const int* __restrict__ tn,
             const int* __restrict__ tm,
             const float* __restrict__ slotwt)
{
  constexpr int KD = (MODE == 0) ? DIMD : (MODE == 1) ? HSH : (MODE == 2) ? DIMD : HE;
  constexpr int ND = (MODE == 0) ? 2 * HSH : (MODE == 1) ? DIMD : (MODE == 2) ? HSH : DIMD;
  constexpr bool FUSE = (MODE == 0 || MODE == 2);
  constexpr int NDOUT = (MODE == 0) ? HSH : (MODE == 2) ? HE : ND;

  __shared__ __align__(16) char sMemRaw[FUSE ? 33792 : 32768];
  u16* sA = (u16*)sMemRaw;
  u16* sB = sA + 128 * 64;

  const int tid  = threadIdx.x;
  const int lane = tid & 63;
  const int wave = tid >> 6;
  const int wm = wave >> 1, wn = wave & 1;

  int mbase, nbase;
  int e = 0, cnt = 0, arow0;
  const u16* B = Bg;
  if constexpr (MODE >= 2) {
    int tix = blockIdx.x;
    e = te[tix];
    if (e < 0) return;
    cnt = counts[e];
    mbase = tm[tix];
    nbase = tn[tix] * 128;
    arow0 = offs[e] + mbase;
    B = Bg + (size_t)e * ND * KD;
  } else {
    const int nx = gridDim.x;
    int bid = blockIdx.y * nx + blockIdx.x;
    int cpx = (nx * gridDim.y) >> 3;
    int swz = (bid & 7) * cpx + (bid >> 3);
    mbase = (swz / nx) * 128;
    nbase = (swz % nx) * 128;
    arow0 = mbase;
  }

  f32x4 acc[4][4];
#pragma unroll
  for (int i = 0; i < 4; ++i)
#pragma unroll
    for (int j = 0; j < 4; ++j) acc[i][j] = (f32x4){0.f, 0.f, 0.f, 0.f};

  const int srow  = lane >> 3;
  const int sslot = (lane & 7) ^ srow;
  const int scol  = sslot * 8;

  const u16* Bbase = B + (size_t)nbase * KD;

  for (int kb = 0; kb < KD; kb += 64) {
#pragma unroll
    for (int i = 0; i < 4; ++i) {
      int c = wave * 4 + i;
      int row = c * 8 + srow;
      size_t ar;
      if constexpr (MODE >= 2) {
        int rg = arow0 + row;
        if (rg > SLOTS - 1) rg = SLOTS - 1;
        ar = (size_t)rg * KD;
      } else {
        ar = (size_t)(arow0 + row) * KD;
      }
      gload_lds16(A + ar + kb + scol, &sA[c * 512]);
      gload_lds16(Bbase + (size_t)row * KD + kb + scol, &sB[c * 512]);
    }
    __syncthreads();

#pragma unroll
    for (int ks = 0; ks < 2; ++ks) {
      bf16x8 a[4], b[4];
#pragma unroll
      for (int mi = 0; mi < 4; ++mi) {
        int r = wm * 64 + mi * 16 + (lane & 15);
        int s = (ks * 4 + (lane >> 4)) ^ (r & 7);
        a[mi] = *(const bf16x8*)((const char*)sA + r * 128 + s * 16);
      }
#pragma unroll
      for (int ni = 0; ni < 4; ++ni) {
        int r = wn * 64 + ni * 16 + (lane & 15);
        int s = (ks * 4 + (lane >> 4)) ^ (r & 7);
        b[ni] = *(const bf16x8*)((const char*)sB + r * 128 + s * 16);
      }
#pragma unroll
      for (int mi = 0; mi < 4; ++mi)
#pragma unroll
        for (int ni = 0; ni < 4; ++ni)
          acc[mi][ni] = __builtin_amdgcn_mfma_f32_16x16x32_bf16(a[mi], b[ni], acc[mi][ni], 0, 0, 0);
    }
    __syncthreads();
  }

  const int lr4 = (lane >> 4) * 4;
  const int lc  = lane & 15;

  if constexpr (FUSE) {
    float* sX = (float*)sMemRaw;   // [128][66] f32
    if (wn == 1) {
#pragma unroll
      for (int mi = 0; mi < 4; ++mi)
#pragma unroll
        for (int ni = 0; ni < 4; ++ni)
#pragma unroll
          for (int r = 0; r < 4; ++r)
            sX[(wm * 64 + mi * 16 + lr4 + r) * 66 + ni * 16 + lc] = acc[mi][ni][r];
    }
    __syncthreads();
    if (wn == 0) {
#pragma unroll
      for (int mi = 0; mi < 4; ++mi) {
#pragma unroll
        for (int ni = 0; ni < 4; ++ni) {
#pragma unroll
          for (int r = 0; r < 4; ++r) {
            int lrow = wm * 64 + mi * 16 + lr4 + r;
            float h1 = acc[mi][ni][r];
            float h3 = sX[lrow * 66 + ni * 16 + lc];
            float u = (h1 / (1.f + __expf(-h1))) * h3;
            int col = (nbase >> 1) + ni * 16 + lc;
            if constexpr (MODE == 0) {
              Obf[(size_t)(mbase + lrow) * NDOUT + col] = f2bf(u);
            } else {
              int grow = mbase + lrow;
              if (grow < cnt) {
                u *= slotwt[arow0 + lrow];
                Obf[(size_t)(arow0 + lrow) * NDOUT + col] = f2bf(u);
              }
            }
          }
        }
      }
    }
  } else {
#pragma unroll
    for (int mi = 0; mi < 4; ++mi) {
#pragma unroll
      for (int ni = 0; ni < 4; ++ni) {
#pragma unroll
        for (int r = 0; r < 4; ++r) {
          int lrow = wm * 64 + mi * 16 + lr4 + r;
          int col  = nbase + wn * 64 + ni * 16 + lc;
          float v = acc[mi][ni][r];
          if constexpr (MODE == 1) {
            Of[(size_t)(mbase + lrow) * ND + col] = v;
          } else {
            int grow = mbase + lrow;
            if (grow < cnt) Obf[(size_t)(arow0 + lrow) * ND + col] = f2bf(v);
          }
        }
      }
    }
  }
}

// ------------- finalize: out[t] += Yslot[s0(t)] + Yslot[s1(t)] -------------
__global__ __launch_bounds__(256)
void finalize(const u16* __restrict__ Yslot, const int* __restrict__ tokslot,
              float* __restrict__ out)
{
  int i = blockIdx.x * 256 + threadIdx.x;
  int t = i >> 8;
  int c = (i & 255) * 8;
  int s0 = tokslot[2 * t], s1 = tokslot[2 * t + 1];
  uint4 a = *(const uint4*)(Yslot + (size_t)s0 * DIMD + c);
  uint4 b = *(const uint4*)(Yslot + (size_t)s1 * DIMD + c);
  const u16* ap = (const u16*)&a;
  const u16* bp = (const u16*)&b;
  float* op = out + (size_t)t * DIMD + c;
  float4 v0 = *(float4*)op, v1 = *(float4*)(op + 4);
  float vv[8] = {v0.x, v0.y, v0.z, v0.w, v1.x, v1.y, v1.z, v1.w};
#pragma unroll
  for (int j = 0; j < 8; ++j) vv[j] += bf2f(ap[j]) + bf2f(bp[j]);
  *(float4*)op = (float4){vv[0], vv[1], vv[2], vv[3]};
  *(float4*)(op + 4) = (float4){vv[4], vv[5], vv[6], vv[7]};
}

extern "C" void kernel_launch(void* const* d_in, const int* in_sizes, int n_in,
                              void* d_out, int out_size, void* d_ws, size_t ws_size,
                              hipStream_t stream) {
  const float* x      = (const float*)d_in[0];
  const float* gate_w = (const float*)d_in[1];
  const float* w1     = (const float*)d_in[2];
  const float* w2     = (const float*)d_in[3];
  const float* w3     = (const float*)d_in[4];
  const float* sw1    = (const float*)d_in[5];
  const float* sw2    = (const float*)d_in[6];
  const float* sw3    = (const float*)d_in[7];
  float* out = (float*)d_out;

  char* ws = (char*)d_ws;
  size_t o = 0;
  int*   counts   = (int*)(ws + o);   o += 256;
  int*   offsv    = (int*)(ws + o);   o += 256;
  float* loadsum  = (float*)(ws + o); o += 256;
  int*   te2      = (int*)(ws + o);   o += MAXT * 4;
  int*   tn2      = (int*)(ws + o);   o += MAXT * 4;
  int*   tm2      = (int*)(ws + o);   o += MAXT * 4;
  int*   te3      = (int*)(ws + o);   o += MAXT * 4;
  int*   tn3      = (int*)(ws + o);   o += MAXT * 4;
  int*   tm3      = (int*)(ws + o);   o += MAXT * 4;
  int*   sel0     = (int*)(ws + o);   o += TOKS * 4;
  int*   sel1     = (int*)(ws + o);   o += TOKS * 4;
  float* wt0      = (float*)(ws + o); o += TOKS * 4;
  float* wt1      = (float*)(ws + o); o += TOKS * 4;
  int*   tokslot  = (int*)(ws + o);   o += TOKS * 2 * 4;
  int*   toklist2 = (int*)(ws + o);   o += SLOTS * 4;
  float* slotwt   = (float*)(ws + o); o += SLOTS * 4;
  float* probs    = (float*)(ws + o); o += TOKS * 16 * 4;

  o = 1 << 20;
  u16* xbf   = (u16*)(ws + o); o += (size_t)TOKS * DIMD * 2;
  u16* Xg    = (u16*)(ws + o); o += (size_t)SLOTP * DIMD * 2;
  u16* w13b  = (u16*)(ws + o); o += (size_t)NE * HSH * DIMD * 2;
  u16* w2b   = (u16*)(ws + o); o += (size_t)NE * DIMD * HE * 2;
  u16* sw13b = (u16*)(ws + o); o += (size_t)(2 * HSH) * DIMD * 2;
  u16* sw2b  = (u16*)(ws + o); o += (size_t)DIMD * HSH * 2;
  u16* UA    = (u16*)(ws + o); o += (size_t)SLOTP * HSH * 2;
  u16* Yslot = Xg;  // Xg dead after gemm<2>

  // routing (fully deterministic, no atomics); gate also emits xbf
  gate2_kernel<<<TOKS, 64, 0, stream>>>(x, gate_w, probs, sel0, sel1, wt0, wt1, xbf);
  expert_count<<<NE, 256, 0, stream>>>(sel0, sel1, wt0, wt1, counts, loadsum);
  offsets_aux<<<1, 256, 0, stream>>>(probs, counts, loadsum, offsv,
                                     te2, tn2, tm2, te3, tn3, tm3,
                                     out + (size_t)TOKS * DIMD);
  rank_scatter<<<NE, 256, 0, stream>>>(sel0, sel1, wt0, wt1, offsv, toklist2, slotwt, tokslot);

  // bf16 weight conversions (w1/w3, sw1/sw3 interleaved in 64-row chunks for fused silu)
  cvt_pair<<<2048, 256, 0, stream>>>((const float4*)sw1, (const float4*)sw3, (uint2*)sw13b,
                                     HSH, DIMD / 4, 0, HSH * DIMD / 4);
  cvt_f32_bf16<<<1024, 256, 0, stream>>>((const float4*)sw2, (uint2*)sw2b, DIMD * HSH / 4);
  cvt_f32_bf16<<<4096, 256, 0, stream>>>((const float4*)w2, (uint2*)w2b, NE * DIMD * HE / 4);
  cvt_pair<<<4096, 256, 0, stream>>>((const float4*)w1, (const float4*)w3, (uint2*)w13b,
                                     HE, DIMD / 4, HSH * DIMD / 4, NE * HE * DIMD / 4);
  gather2<<<SLOTS / 4, 256, 0, stream>>>(xbf, toklist2, Xg);

  // shared expert: fused h1/h3 -> U, then U @ sw2^T -> out
  gemm128<0><<<dim3(2 * HSH / 128, TOKS / 128), 256, 0, stream>>>(
      xbf, sw13b, UA, nullptr, nullptr, nullptr, nullptr, nullptr, nullptr, nullptr);
  gemm128<1><<<dim3(DIMD / 128, TOKS / 128), 256, 0, stream>>>(
      UA, sw2b, nullptr, out, nullptr, nullptr, nullptr, nullptr, nullptr, nullptr);

  // routed experts: XCD-packed tables, fixed grid (sentinel early-exit)
  gemm128<2><<<dim3(MAXT), 256, 0, stream>>>(
      Xg, w13b, UA, nullptr, counts, offsv, te2, tn2, tm2, slotwt);
  gemm128<3><<<dim3(MAXT), 256, 0, stream>>>(
      UA, w2b, Yslot, nullptr, counts, offsv, te3, tn3, tm3, nullptr);
  finalize<<<TOKS * DIMD / 8 / 256, 256, 0, stream>>>(Yslot, tokslot, out);
}

// Round 16
// 749.232 us; speedup vs baseline: 1.4531x; 1.0136x over previous
//
#include <hip/hip_runtime.h>
#include <cstdint>

#define TOKS 4096
#define DIMD 2048
#define NE   16
#define HE   1408
#define HSH  2816
#define SLOTS 8192
#define SLOTP 8320
#define MAXT 2048

typedef unsigned short u16;
typedef __attribute__((ext_vector_type(8))) __bf16 bf16x8;
typedef __attribute__((ext_vector_type(4))) float  f32x4;

__device__ inline unsigned f2bf_pack(float a, float b) {
  unsigned ua = __builtin_bit_cast(unsigned, a);
  unsigned ub = __builtin_bit_cast(unsigned, b);
  ua = (ua + 0x7FFFu + ((ua >> 16) & 1u)) >> 16;
  ub = (ub + 0x7FFFu + ((ub >> 16) & 1u)) >> 16;
  return ua | (ub << 16);
}
__device__ inline u16 f2bf(float a) {
  unsigned ua = __builtin_bit_cast(unsigned, a);
  return (u16)((ua + 0x7FFFu + ((ua >> 16) & 1u)) >> 16);
}
__device__ inline float bf2f(u16 u) {
  return __builtin_bit_cast(float, (unsigned)u << 16);
}
__device__ inline void gload_lds16(const u16* g, u16* l) {
  __builtin_amdgcn_global_load_lds((const __attribute__((address_space(1))) void*)g,
                                   (__attribute__((address_space(3))) void*)l, 16, 0, 0);
}

// ---------------- gate (also emits xbf = bf16(x) as side output) ----------------
__global__ __launch_bounds__(64)
void gate2_kernel(const float* __restrict__ x, const float* __restrict__ gw,
                  float* __restrict__ probs, int* __restrict__ sel0, int* __restrict__ sel1,
                  float* __restrict__ wt0, float* __restrict__ wt1,
                  u16* __restrict__ xbf)
{
  const int t = blockIdx.x;
  const int l = threadIdx.x;
  const float4* xr = (const float4*)(x + (size_t)t * DIMD);
  float4 xv[8];
#pragma unroll
  for (int j = 0; j < 8; ++j) xv[j] = xr[j * 64 + l];

  uint2* xo = (uint2*)(xbf + (size_t)t * DIMD);
#pragma unroll
  for (int j = 0; j < 8; ++j) {
    uint2 q; q.x = f2bf_pack(xv[j].x, xv[j].y); q.y = f2bf_pack(xv[j].z, xv[j].w);
    xo[j * 64 + l] = q;
  }

  float sc[16];
#pragma unroll
  for (int e = 0; e < 16; ++e) {
    const float4* g = (const float4*)(gw + (size_t)e * DIMD);
    float s = 0.f;
#pragma unroll
    for (int j = 0; j < 8; ++j) {
      float4 gv = g[j * 64 + l];
      s += xv[j].x * gv.x + xv[j].y * gv.y + xv[j].z * gv.z + xv[j].w * gv.w;
    }
#pragma unroll
    for (int o = 32; o > 0; o >>= 1) s += __shfl_down(s, o);
    sc[e] = s;
  }
  if (l == 0) {
    float mx = sc[0];
#pragma unroll
    for (int e = 1; e < 16; ++e) mx = fmaxf(mx, sc[e]);
    float pe[16]; float sum = 0.f;
#pragma unroll
    for (int e = 0; e < 16; ++e) { pe[e] = __expf(sc[e] - mx); sum += pe[e]; }
    float inv = 1.f / sum;
    int b0 = -1, b1 = -1; float v0 = -1.f, v1 = -1.f;
#pragma unroll
    for (int e = 0; e < 16; ++e) {
      float p = pe[e] * inv;
      probs[t * 16 + e] = p;
      if (p > v0) { v1 = v0; b1 = b0; v0 = p; b0 = e; }
      else if (p > v1) { v1 = p; b1 = e; }
    }
    float wsum = v0 + v1 + 1e-9f;
    sel0[t] = b0; sel1[t] = b1;
    wt0[t] = v0 / wsum; wt1[t] = v1 / wsum;
  }
}

// ------------- per-expert count + load sum -------------
__global__ __launch_bounds__(256)
void expert_count(const int* __restrict__ sel0, const int* __restrict__ sel1,
                  const float* __restrict__ wt0, const float* __restrict__ wt1,
                  int* __restrict__ counts, float* __restrict__ loadsum)
{
  const int e = blockIdx.x, tid = threadIdx.x;
  int c = 0; float s = 0.f;
  for (int t = tid; t < TOKS; t += 256) {
    if (sel0[t] == e) { c++; s += wt0[t]; }
    else if (sel1[t] == e) { c++; s += wt1[t]; }
  }
  __shared__ int ci[256]; __shared__ float sf[256];
  ci[tid] = c; sf[tid] = s; __syncthreads();
  for (int d = 128; d > 0; d >>= 1) {
    if (tid < d) { ci[tid] += ci[tid + d]; sf[tid] += sf[tid + d]; }
    __syncthreads();
  }
  if (tid == 0) { counts[e] = ci[0]; loadsum[e] = sf[0]; }
}

// --- offsets + aux + XCD-packed tile tables (parallel scatter) ---
__global__ __launch_bounds__(256)
void offsets_aux(const float* __restrict__ probs, const int* __restrict__ counts,
                 const float* __restrict__ loadsum, int* __restrict__ offs,
                 int* __restrict__ te2, int* __restrict__ tn2, int* __restrict__ tm2,
                 int* __restrict__ te3, int* __restrict__ tn3, int* __restrict__ tm3,
                 float* __restrict__ out_aux)
{
  const int tid = threadIdx.x;
  for (int i = tid; i < MAXT; i += 256) { te2[i] = -1; te3[i] = -1; }

  float imp[16];
#pragma unroll
  for (int e = 0; e < 16; ++e) imp[e] = 0.f;
  for (int t = tid; t < TOKS; t += 256)
#pragma unroll
    for (int e = 0; e < 16; ++e) imp[e] += probs[t * 16 + e];

  __shared__ float red[256];
  __shared__ float impE[16];
  for (int e = 0; e < 16; ++e) {
    red[tid] = imp[e]; __syncthreads();
    for (int d = 128; d > 0; d >>= 1) {
      if (tid < d) red[tid] += red[tid + d];
      __syncthreads();
    }
    if (tid == 0) impE[e] = red[0];
    __syncthreads();
  }

  __shared__ int mtS[16];
  __shared__ int pEN2[352], pXS2[352], np2S;
  __shared__ int pEN3[256], pXS3[256], np3S;

  if (tid == 0) {
    int off = 0;
    for (int e = 0; e < 16; ++e) { offs[e] = off; off += counts[e]; }
    float tot = 0.f;
    for (int e = 0; e < 16; ++e) tot += loadsum[e];
    float aux = 0.f;
    for (int e = 0; e < 16; ++e) aux += (impE[e] / (float)TOKS) * (loadsum[e] / (tot + 1e-9f));
    *out_aux = 16.f * aux;

    int mt[16];
    for (int e = 0; e < 16; ++e) { mt[e] = (counts[e] + 127) >> 7; mtS[e] = mt[e]; }
    {
      int btot = 0;
      for (int e = 0; e < 16; ++e) btot += mt[e] * 22;
      int target = (btot + 7) >> 3;
      int x = 0, sp = 0, p = 0;
      for (int e = 0; e < 16; ++e) {
        if (!mt[e]) continue;
        for (int n = 0; n < 22; ++n) {
          pEN2[p] = e * 32 + n; pXS2[p] = x * 65536 + sp; ++p;
          sp += mt[e];
          if (sp >= target && x < 7) { ++x; sp = 0; }
        }
      }
      np2S = p;
    }
    {
      int btot = 0;
      for (int e = 0; e < 16; ++e) btot += mt[e] * 16;
      int target = (btot + 7) >> 3;
      int x = 0, sp = 0, p = 0;
      for (int e = 0; e < 16; ++e) {
        if (!mt[e]) continue;
        for (int n = 0; n < 16; ++n) {
          pEN3[p] = e * 32 + n; pXS3[p] = x * 65536 + sp; ++p;
          sp += mt[e];
          if (sp >= target && x < 7) { ++x; sp = 0; }
        }
      }
      np3S = p;
    }
  }
  __syncthreads();

  for (int p = tid; p < np2S; p += 256) {
    int e = pEN2[p] >> 5, n = pEN2[p] & 31;
    int x = pXS2[p] >> 16, sp = pXS2[p] & 65535;
    int mte = mtS[e];
    for (int m = 0; m < mte; ++m) {
      int tix = (sp + m) * 8 + x;
      te2[tix] = e; tn2[tix] = n; tm2[tix] = m << 7;
    }
  }
  for (int p = tid; p < np3S; p += 256) {
    int e = pEN3[p] >> 5, n = pEN3[p] & 31;
    int x = pXS3[p] >> 16, sp = pXS3[p] & 65535;
    int mte = mtS[e];
    for (int m = 0; m < mte; ++m) {
      int tix = (sp + m) * 8 + x;
      te3[tix] = e; tn3[tix] = n; tm3[tix] = m << 7;
    }
  }
}

// ------------- deterministic rank + scatter -------------
__global__ __launch_bounds__(256)
void rank_scatter(const int* __restrict__ sel0, const int* __restrict__ sel1,
                  const float* __restrict__ wt0, const float* __restrict__ wt1,
                  const int* __restrict__ offs, int* __restrict__ toklist2,
                  float* __restrict__ slotwt, int* __restrict__ tokslot)
{
  const int e = blockIdx.x, tid = threadIdx.x;
  const int t0 = tid * 16;
  unsigned flags = 0; int cloc = 0;
#pragma unroll
  for (int j = 0; j < 16; ++j) {
    int t = t0 + j;
    bool f = (sel0[t] == e) || (sel1[t] == e);
    flags |= ((unsigned)f) << j;
    cloc += f;
  }
  __shared__ int psum[256];
  psum[tid] = cloc; __syncthreads();
  for (int d = 1; d < 256; d <<= 1) {
    int v = (tid >= d) ? psum[tid - d] : 0;
    __syncthreads();
    psum[tid] += v;
    __syncthreads();
  }
  int r = offs[e] + psum[tid] - cloc;
  for (int j = 0; j < 16; ++j) {
    if ((flags >> j) & 1u) {
      int t = t0 + j;
      bool first = (sel0[t] == e);
      toklist2[r] = t;
      slotwt[r] = first ? wt0[t] : wt1[t];
      tokslot[2 * t + (first ? 0 : 1)] = r;
      r++;
    }
  }
}

// ------------- fp32 -> bf16 convert (contiguous) -------------
__global__ __launch_bounds__(256)
void cvt_f32_bf16(const float4* __restrict__ src, uint2* __restrict__ dst, int n4)
{
  int i = blockIdx.x * 256 + threadIdx.x;
  int stride = gridDim.x * 256;
  for (; i < n4; i += stride) {
    float4 v = src[i];
    uint2 p; p.x = f2bf_pack(v.x, v.y); p.y = f2bf_pack(v.z, v.w);
    dst[i] = p;
  }
}

// --- paired convert with 64-row chunk interleave ---
__global__ __launch_bounds__(256)
void cvt_pair(const float4* __restrict__ src1, const float4* __restrict__ src3,
              uint2* __restrict__ dst, int rows, int k4, int dstride4, int total4)
{
  int i = blockIdx.x * 256 + threadIdx.x;
  int stride = gridDim.x * 256;
  int per_e = rows * k4;
  for (; i < total4; i += stride) {
    int e = i / per_e;
    int rem = i - e * per_e;
    int j = rem / k4;
    int c = rem - j * k4;
    size_t dbase = (size_t)e * dstride4 + (size_t)(((j >> 6) * 128 + (j & 63))) * k4 + c;
    float4 v1 = src1[i];
    uint2 p1; p1.x = f2bf_pack(v1.x, v1.y); p1.y = f2bf_pack(v1.z, v1.w);
    dst[dbase] = p1;
    float4 v3 = src3[i];
    uint2 p3; p3.x = f2bf_pack(v3.x, v3.y); p3.y = f2bf_pack(v3.z, v3.w);
    dst[dbase + (size_t)64 * k4] = p3;
  }
}

// ------------- gather: copy bf16 token rows into slot-major layout -------------
__global__ __launch_bounds__(256)
void gather2(const u16* __restrict__ xbf, const int* __restrict__ toklist2,
             u16* __restrict__ Xg)
{
  int slot = blockIdx.x * 4 + (threadIdx.x >> 6);
  int l = threadIdx.x & 63;
  int tok = toklist2[slot];
  const uint2* srcr = (const uint2*)(xbf + (size_t)tok * DIMD);
  uint2* dstr = (uint2*)(Xg + (size_t)slot * DIMD);
#pragma unroll
  for (int j = 0; j < 8; ++j) dstr[j * 64 + l] = srcr[j * 64 + l];
}

// ------------- single-B bf16 MFMA GEMM (C = A * B^T), 128x128, BK=64 -------------
// MODE 0: dense A=xbf,B=sw13b(interleaved) -> fused silu -> U bf16
// MODE 1: dense A=U,B=sw2b -> out f32 (+ fused finalize: adds Yslot[s0]+Yslot[s1])
// MODE 2: grouped A=Xg,B=w13b[e] -> fused silu*wt -> Act (XCD-packed table)
// MODE 3: grouped A=Act,B=w2b[e] -> Yslot bf16 (XCD-packed table)
template<int MODE>
__global__ __launch_bounds__(256, 4)
void gemm128(const u16* __restrict__ A, const u16* __restrict__ Bg,
             u16* __restrict__ Obf, float* __restrict__ Of,
             const int* __restrict__ counts, const int* __restrict__ offs,
             const int* __restrict__ te, const int* __restrict__ tn,
             const int* __restrict__ tm,
             const float* __restrict__ slotwt,
             const int* __restrict__ tokslot, const u16* __restrict__ Yin)
{
  constexpr int KD = (MODE == 0) ? DIMD : (MODE == 1) ? HSH : (MODE == 2) ? DIMD : HE;
  constexpr int ND = (MODE == 0) ? 2 * HSH : (MODE == 1) ? DIMD : (MODE == 2) ? HSH : DIMD;
  constexpr bool FUSE = (MODE == 0 || MODE == 2);
  constexpr int NDOUT = (MODE == 0) ? HSH : (MODE == 2) ? HE : ND;

  __shared__ __align__(16) char sMemRaw[FUSE ? 33792 : 32768];
  u16* sA = (u16*)sMemRaw;
  u16* sB = sA + 128 * 64;

  const int tid  = threadIdx.x;
  const int lane = tid & 63;
  const int wave = tid >> 6;
  const int wm = wave >> 1, wn = wave & 1;

  int mbase, nbase;
  int e = 0, cnt = 0, arow0;
  const u16* B = Bg;
  if constexpr (MODE >= 2) {
    int tix = blockIdx.x;
    e = te[tix];
    if (e < 0) return;
    cnt = counts[e];
    mbase = tm[tix];
    nbase = tn[tix] * 128;
    arow0 = offs[e] + mbase;
    B = Bg + (size_t)e * ND * KD;
  } else {
    const int nx = gridDim.x;
    int bid = blockIdx.y * nx + blockIdx.x;
    int cpx = (nx * gridDim.y) >> 3;
    int swz = (bid & 7) * cpx + (bid >> 3);
    mbase = (swz / nx) * 128;
    nbase = (swz % nx) * 128;
    arow0 = mbase;
  }

  f32x4 acc[4][4];
#pragma unroll
  for (int i = 0; i < 4; ++i)
#pragma unroll
    for (int j = 0; j < 4; ++j) acc[i][j] = (f32x4){0.f, 0.f, 0.f, 0.f};

  const int srow  = lane >> 3;
  const int sslot = (lane & 7) ^ srow;
  const int scol  = sslot * 8;

  const u16* Bbase = B + (size_t)nbase * KD;

  for (int kb = 0; kb < KD; kb += 64) {
#pragma unroll
    for (int i = 0; i < 4; ++i) {
      int c = wave * 4 + i;
      int row = c * 8 + srow;
      size_t ar;
      if constexpr (MODE >= 2) {
        int rg = arow0 + row;
        if (rg > SLOTS - 1) rg = SLOTS - 1;
        ar = (size_t)rg * KD;
      } else {
        ar = (size_t)(arow0 + row) * KD;
      }
      gload_lds16(A + ar + kb + scol, &sA[c * 512]);
      gload_lds16(Bbase + (size_t)row * KD + kb + scol, &sB[c * 512]);
    }
    __syncthreads();

#pragma unroll
    for (int ks = 0; ks < 2; ++ks) {
      bf16x8 a[4], b[4];
#pragma unroll
      for (int mi = 0; mi < 4; ++mi) {
        int r = wm * 64 + mi * 16 + (lane & 15);
        int s = (ks * 4 + (lane >> 4)) ^ (r & 7);
        a[mi] = *(const bf16x8*)((const char*)sA + r * 128 + s * 16);
      }
#pragma unroll
      for (int ni = 0; ni < 4; ++ni) {
        int r = wn * 64 + ni * 16 + (lane & 15);
        int s = (ks * 4 + (lane >> 4)) ^ (r & 7);
        b[ni] = *(const bf16x8*)((const char*)sB + r * 128 + s * 16);
      }
#pragma unroll
      for (int mi = 0; mi < 4; ++mi)
#pragma unroll
        for (int ni = 0; ni < 4; ++ni)
          acc[mi][ni] = __builtin_amdgcn_mfma_f32_16x16x32_bf16(a[mi], b[ni], acc[mi][ni], 0, 0, 0);
    }
    __syncthreads();
  }

  const int lr4 = (lane >> 4) * 4;
  const int lc  = lane & 15;

  if constexpr (FUSE) {
    float* sX = (float*)sMemRaw;   // [128][66] f32
    if (wn == 1) {
#pragma unroll
      for (int mi = 0; mi < 4; ++mi)
#pragma unroll
        for (int ni = 0; ni < 4; ++ni)
#pragma unroll
          for (int r = 0; r < 4; ++r)
            sX[(wm * 64 + mi * 16 + lr4 + r) * 66 + ni * 16 + lc] = acc[mi][ni][r];
    }
    __syncthreads();
    if (wn == 0) {
#pragma unroll
      for (int mi = 0; mi < 4; ++mi) {
#pragma unroll
        for (int ni = 0; ni < 4; ++ni) {
#pragma unroll
          for (int r = 0; r < 4; ++r) {
            int lrow = wm * 64 + mi * 16 + lr4 + r;
            float h1 = acc[mi][ni][r];
            float h3 = sX[lrow * 66 + ni * 16 + lc];
            float u = (h1 / (1.f + __expf(-h1))) * h3;
            int col = (nbase >> 1) + ni * 16 + lc;
            if constexpr (MODE == 0) {
              Obf[(size_t)(mbase + lrow) * NDOUT + col] = f2bf(u);
            } else {
              int grow = mbase + lrow;
              if (grow < cnt) {
                u *= slotwt[arow0 + lrow];
                Obf[(size_t)(arow0 + lrow) * NDOUT + col] = f2bf(u);
              }
            }
          }
        }
      }
    }
  } else {
#pragma unroll
    for (int mi = 0; mi < 4; ++mi) {
#pragma unroll
      for (int ni = 0; ni < 4; ++ni) {
#pragma unroll
        for (int r = 0; r < 4; ++r) {
          int lrow = wm * 64 + mi * 16 + lr4 + r;
          int col  = nbase + wn * 64 + ni * 16 + lc;
          float v = acc[mi][ni][r];
          if constexpr (MODE == 1) {
            // fused finalize: add both routed contributions for this token
            int t = mbase + lrow;
            int s0 = tokslot[2 * t], s1 = tokslot[2 * t + 1];
            float u = v + bf2f(Yin[(size_t)s0 * DIMD + col]);
            u = u + bf2f(Yin[(size_t)s1 * DIMD + col]);
            Of[(size_t)t * ND + col] = u;
          } else {
            int grow = mbase + lrow;
            if (grow < cnt) Obf[(size_t)(arow0 + lrow) * ND + col] = f2bf(v);
          }
        }
      }
    }
  }
}

extern "C" void kernel_launch(void* const* d_in, const int* in_sizes, int n_in,
                              void* d_out, int out_size, void* d_ws, size_t ws_size,
                              hipStream_t stream) {
  const float* x      = (const float*)d_in[0];
  const float* gate_w = (const float*)d_in[1];
  const float* w1     = (const float*)d_in[2];
  const float* w2     = (const float*)d_in[3];
  const float* w3     = (const float*)d_in[4];
  const float* sw1    = (const float*)d_in[5];
  const float* sw2    = (const float*)d_in[6];
  const float* sw3    = (const float*)d_in[7];
  float* out = (float*)d_out;

  char* ws = (char*)d_ws;
  size_t o = 0;
  int*   counts   = (int*)(ws + o);   o += 256;
  int*   offsv    = (int*)(ws + o);   o += 256;
  float* loadsum  = (float*)(ws + o); o += 256;
  int*   te2      = (int*)(ws + o);   o += MAXT * 4;
  int*   tn2      = (int*)(ws + o);   o += MAXT * 4;
  int*   tm2      = (int*)(ws + o);   o += MAXT * 4;
  int*   te3      = (int*)(ws + o);   o += MAXT * 4;
  int*   tn3      = (int*)(ws + o);   o += MAXT * 4;
  int*   tm3      = (int*)(ws + o);   o += MAXT * 4;
  int*   sel0     = (int*)(ws + o);   o += TOKS * 4;
  int*   sel1     = (int*)(ws + o);   o += TOKS * 4;
  float* wt0      = (float*)(ws + o); o += TOKS * 4;
  float* wt1      = (float*)(ws + o); o += TOKS * 4;
  int*   tokslot  = (int*)(ws + o);   o += TOKS * 2 * 4;
  int*   toklist2 = (int*)(ws + o);   o += SLOTS * 4;
  float* slotwt   = (float*)(ws + o); o += SLOTS * 4;
  float* probs    = (float*)(ws + o); o += TOKS * 16 * 4;

  o = 1 << 20;
  u16* xbf   = (u16*)(ws + o); o += (size_t)TOKS * DIMD * 2;
  u16* Xg    = (u16*)(ws + o); o += (size_t)SLOTP * DIMD * 2;
  u16* w13b  = (u16*)(ws + o); o += (size_t)NE * HSH * DIMD * 2;
  u16* w2b   = (u16*)(ws + o); o += (size_t)NE * DIMD * HE * 2;
  u16* sw13b = (u16*)(ws + o); o += (size_t)(2 * HSH) * DIMD * 2;
  u16* sw2b  = (u16*)(ws + o); o += (size_t)DIMD * HSH * 2;
  u16* UA    = (u16*)(ws + o); o += (size_t)SLOTP * HSH * 2;
  u16* Yslot = Xg;  // Xg dead after gemm<2>; gemm<3> writes here; gemm<1> reads

  // routing (fully deterministic, no atomics); gate also emits xbf
  gate2_kernel<<<TOKS, 64, 0, stream>>>(x, gate_w, probs, sel0, sel1, wt0, wt1, xbf);
  expert_count<<<NE, 256, 0, stream>>>(sel0, sel1, wt0, wt1, counts, loadsum);
  offsets_aux<<<1, 256, 0, stream>>>(probs, counts, loadsum, offsv,
                                     te2, tn2, tm2, te3, tn3, tm3,
                                     out + (size_t)TOKS * DIMD);
  rank_scatter<<<NE, 256, 0, stream>>>(sel0, sel1, wt0, wt1, offsv, toklist2, slotwt, tokslot);

  // bf16 weight conversions, ordered so every GEMM's B is "recently converted
  // with >=1 intervening kernel" (R13 property; avoids R14 dirty-writeback adjacency)
  cvt_pair<<<4096, 256, 0, stream>>>((const float4*)w1, (const float4*)w3, (uint2*)w13b,
                                     HE, DIMD / 4, HSH * DIMD / 4, NE * HE * DIMD / 4);
  cvt_f32_bf16<<<4096, 256, 0, stream>>>((const float4*)w2, (uint2*)w2b, NE * DIMD * HE / 4);
  cvt_pair<<<2048, 256, 0, stream>>>((const float4*)sw1, (const float4*)sw3, (uint2*)sw13b,
                                     HSH, DIMD / 4, 0, HSH * DIMD / 4);
  cvt_f32_bf16<<<1024, 256, 0, stream>>>((const float4*)sw2, (uint2*)sw2b, DIMD * HSH / 4);
  gather2<<<SLOTS / 4, 256, 0, stream>>>(xbf, toklist2, Xg);

  // routed experts first (Yslot ready before shared-expert MODE1 consumes it)
  gemm128<2><<<dim3(MAXT), 256, 0, stream>>>(
      Xg, w13b, UA, nullptr, counts, offsv, te2, tn2, tm2, slotwt, nullptr, nullptr);
  gemm128<3><<<dim3(MAXT), 256, 0, stream>>>(
      UA, w2b, Yslot, nullptr, counts, offsv, te3, tn3, tm3, nullptr, nullptr, nullptr);

  // shared expert: fused h1/h3 -> U, then U @ sw2^T + routed sum -> out
  gemm128<0><<<dim3(2 * HSH / 128, TOKS / 128), 256, 0, stream>>>(
      xbf, sw13b, UA, nullptr, nullptr, nullptr, nullptr, nullptr, nullptr, nullptr, nullptr, nullptr);
  gemm128<1><<<dim3(DIMD / 128, TOKS / 128), 256, 0, stream>>>(
      UA, sw2b, nullptr, out, nullptr, nullptr, nullptr, nullptr, nullptr, nullptr, tokslot, Yslot);
}